// Round 1
// baseline (666.075 us; speedup 1.0000x reference)
//
#include <hip/hip_runtime.h>
#include <float.h>
#include <math.h>

#define NNODES 100000
#define NEDGES 800000
#define NF 128
#define NLAYERS 3
#define NCLASSES 10
#define NGRAPHS 256

// ---------------- degree histogram (dst occurrences) ----------------
__global__ __launch_bounds__(256) void hist_kernel(const int* __restrict__ dst,
                                                   unsigned* __restrict__ cnt, int E) {
    int i = blockIdx.x * 256 + threadIdx.x;
    if (i < E) atomicAdd(&cnt[dst[i]], 1u);
}

// ---------------- dinv = rsqrt(in_deg + 1)  (self-loop included) ----------------
__global__ __launch_bounds__(256) void dinv_kernel(const unsigned* __restrict__ cnt,
                                                   float* __restrict__ dinv, int N) {
    int i = blockIdx.x * 256 + threadIdx.x;
    if (i < N) dinv[i] = rsqrtf((float)cnt[i] + 1.0f);
}

// ---------------- exclusive prefix sum over cnt -> rowptr, cursor ----------------
// single block, 1024 threads, wave-shuffle scan (3 barriers per 1024-chunk)
__global__ __launch_bounds__(1024) void scan_kernel(const unsigned* __restrict__ cnt,
                                                    unsigned* __restrict__ rowptr,
                                                    unsigned* __restrict__ cursor, int N) {
    __shared__ unsigned wsum[16];
    __shared__ unsigned wpre[16];
    int tid = threadIdx.x;
    int wid = tid >> 6, lane = tid & 63;
    unsigned carry = 0;
    for (int base = 0; base < N; base += 1024) {
        int i = base + tid;
        unsigned v = (i < N) ? cnt[i] : 0u;
        unsigned incl = v;
        #pragma unroll
        for (int off = 1; off < 64; off <<= 1) {
            unsigned t = __shfl_up(incl, off, 64);
            if (lane >= off) incl += t;
        }
        if (lane == 63) wsum[wid] = incl;
        __syncthreads();
        if (tid < 16) {
            unsigned s = wsum[tid];
            unsigned inc2 = s;
            #pragma unroll
            for (int off = 1; off < 16; off <<= 1) {
                unsigned t = __shfl_up(inc2, off, 64);
                if (tid >= off) inc2 += t;
            }
            wpre[tid] = inc2 - s;  // exclusive prefix of wave sums
        }
        __syncthreads();
        unsigned excl = incl - v + wpre[wid] + carry;
        if (i < N) { rowptr[i] = excl; cursor[i] = excl; }
        unsigned total = wpre[15] + wsum[15];
        __syncthreads();  // protect wsum/wpre before next chunk overwrites
        carry += total;
    }
    if (tid == 0) rowptr[N] = carry;
}

// ---------------- CSR fill: per edge, slot = cursor[dst]++ ----------------
__global__ __launch_bounds__(256) void fill_kernel(const int* __restrict__ src,
                                                   const int* __restrict__ dst,
                                                   const float* __restrict__ dinv,
                                                   unsigned* __restrict__ cursor,
                                                   unsigned* __restrict__ csr_src,
                                                   float* __restrict__ csr_norm, int E) {
    int e = blockIdx.x * 256 + threadIdx.x;
    if (e < E) {
        int s = src[e], d = dst[e];
        unsigned pos = atomicAdd(&cursor[d], 1u);
        csr_src[pos] = (unsigned)s;
        csr_norm[pos] = dinv[s] * dinv[d];
    }
}

// ---------------- H = X @ W   (M x 128) @ (128 x 128), fp32 ----------------
// 64-row tile; W staged in LDS in two 64-col halves (64KB LDS total -> 2 blocks/CU)
__global__ __launch_bounds__(256) void gemm_kernel(const float* __restrict__ X,
                                                   const float* __restrict__ W,
                                                   float* __restrict__ H, int M) {
    __shared__ float Xl[64][128];   // 32 KB
    __shared__ float Wl[128][64];   // 32 KB (one N-half)
    int tid = threadIdx.x;
    int row0 = blockIdx.x * 64;

    // load X tile (zero-pad past M)
    for (int i = tid; i < 64 * 32; i += 256) {
        int r = i >> 5, kv = i & 31;
        float4 v = make_float4(0.f, 0.f, 0.f, 0.f);
        int row = row0 + r;
        if (row < M) v = ((const float4*)(X + (size_t)row * NF))[kv];
        ((float4*)Xl[r])[kv] = v;
    }

    int tc = tid & 15, tr = tid >> 4;
    int c0 = tc * 4, r0 = tr * 4;

    for (int nh = 0; nh < 2; ++nh) {
        __syncthreads();
        // load W half: cols nh*64 .. nh*64+63
        for (int i = tid; i < 128 * 16; i += 256) {
            int k = i >> 4, cv = i & 15;
            ((float4*)Wl[k])[cv] = ((const float4*)(W + (size_t)k * NF + nh * 64))[cv];
        }
        __syncthreads();

        float acc[4][4];
        #pragma unroll
        for (int r = 0; r < 4; ++r) { acc[r][0] = 0.f; acc[r][1] = 0.f; acc[r][2] = 0.f; acc[r][3] = 0.f; }

        #pragma unroll 4
        for (int kc = 0; kc < 32; ++kc) {
            int k = kc * 4;
            float4 w0 = *(const float4*)&Wl[k + 0][c0];
            float4 w1 = *(const float4*)&Wl[k + 1][c0];
            float4 w2 = *(const float4*)&Wl[k + 2][c0];
            float4 w3 = *(const float4*)&Wl[k + 3][c0];
            #pragma unroll
            for (int r = 0; r < 4; ++r) {
                float4 xv = *(const float4*)&Xl[r0 + r][k];
                acc[r][0] = fmaf(xv.x, w0.x, fmaf(xv.y, w1.x, fmaf(xv.z, w2.x, fmaf(xv.w, w3.x, acc[r][0]))));
                acc[r][1] = fmaf(xv.x, w0.y, fmaf(xv.y, w1.y, fmaf(xv.z, w2.y, fmaf(xv.w, w3.y, acc[r][1]))));
                acc[r][2] = fmaf(xv.x, w0.z, fmaf(xv.y, w1.z, fmaf(xv.z, w2.z, fmaf(xv.w, w3.z, acc[r][2]))));
                acc[r][3] = fmaf(xv.x, w0.w, fmaf(xv.y, w1.w, fmaf(xv.z, w2.w, fmaf(xv.w, w3.w, acc[r][3]))));
            }
        }
        #pragma unroll
        for (int r = 0; r < 4; ++r) {
            int row = row0 + r0 + r;
            if (row < M)
                *(float4*)&H[(size_t)row * NF + nh * 64 + c0] =
                    make_float4(acc[r][0], acc[r][1], acc[r][2], acc[r][3]);
        }
    }
}

// ---------------- aggregate: Xout = ELU( dinv^2*H[i] + sum_csr norm*H[src] + bias ) ----------------
// 32 lanes per node, float4 per lane
__global__ __launch_bounds__(256) void aggregate_kernel(const float* __restrict__ H,
                                                        const float* __restrict__ dinv,
                                                        const unsigned* __restrict__ rowptr,
                                                        const unsigned* __restrict__ csr_src,
                                                        const float* __restrict__ csr_norm,
                                                        const float* __restrict__ bias,
                                                        float* __restrict__ Xout, int N) {
    int gid = blockIdx.x * 256 + threadIdx.x;
    int node = gid >> 5;
    int lane = gid & 31;
    if (node >= N) return;
    float di = dinv[node];
    float sl = di * di;
    float4 b = ((const float4*)bias)[lane];
    float4 hv = ((const float4*)(H + (size_t)node * NF))[lane];
    float ax = fmaf(hv.x, sl, b.x);
    float ay = fmaf(hv.y, sl, b.y);
    float az = fmaf(hv.z, sl, b.z);
    float aw = fmaf(hv.w, sl, b.w);
    unsigned beg = rowptr[node], end = rowptr[node + 1];
    for (unsigned e = beg; e < end; ++e) {
        unsigned s = csr_src[e];
        float nm = csr_norm[e];
        float4 h2 = ((const float4*)(H + (size_t)s * NF))[lane];
        ax = fmaf(h2.x, nm, ax);
        ay = fmaf(h2.y, nm, ay);
        az = fmaf(h2.z, nm, az);
        aw = fmaf(h2.w, nm, aw);
    }
    // ELU(alpha=1)
    ax = ax > 0.f ? ax : expm1f(ax);
    ay = ay > 0.f ? ay : expm1f(ay);
    az = az > 0.f ? az : expm1f(az);
    aw = aw > 0.f ? aw : expm1f(aw);
    ((float4*)(Xout + (size_t)node * NF))[lane] = make_float4(ax, ay, az, aw);
}

// ---------------- global max pool per graph (batch is sorted) ----------------
__global__ __launch_bounds__(128) void pool_kernel(const float* __restrict__ X,
                                                   const int* __restrict__ batch,
                                                   float* __restrict__ G, int N) {
    int g = blockIdx.x;
    int tid = threadIdx.x;  // column 0..127
    int lo = 0, hi = N;
    while (lo < hi) { int mid = (lo + hi) >> 1; if (batch[mid] < g) lo = mid + 1; else hi = mid; }
    int beg = lo;
    hi = N;
    while (lo < hi) { int mid = (lo + hi) >> 1; if (batch[mid] < g + 1) lo = mid + 1; else hi = mid; }
    int end = lo;
    float m = -FLT_MAX;
    for (int r = beg; r < end; ++r) m = fmaxf(m, X[(size_t)r * NF + tid]);
    G[g * NF + tid] = m;
}

// ---------------- classifier: softmax(G @ Wc + bc) ----------------
__global__ __launch_bounds__(128) void classify_kernel(const float* __restrict__ G,
                                                       const float* __restrict__ Wc,
                                                       const float* __restrict__ bc,
                                                       float* __restrict__ out) {
    __shared__ float gr[NF];
    __shared__ float lg[NCLASSES];
    int g = blockIdx.x;
    int tid = threadIdx.x;
    gr[tid] = G[g * NF + tid];
    __syncthreads();
    if (tid < NCLASSES) {
        float s = bc[tid];
        for (int k = 0; k < NF; ++k) s = fmaf(gr[k], Wc[k * NCLASSES + tid], s);
        lg[tid] = s;
    }
    __syncthreads();
    if (tid == 0) {
        float m = lg[0];
        #pragma unroll
        for (int c = 1; c < NCLASSES; ++c) m = fmaxf(m, lg[c]);
        float e[NCLASSES];
        float sum = 0.f;
        #pragma unroll
        for (int c = 0; c < NCLASSES; ++c) { e[c] = expf(lg[c] - m); sum += e[c]; }
        #pragma unroll
        for (int c = 0; c < NCLASSES; ++c) out[g * NCLASSES + c] = e[c] / sum;
    }
}

extern "C" void kernel_launch(void* const* d_in, const int* in_sizes, int n_in,
                              void* d_out, int out_size, void* d_ws, size_t ws_size,
                              hipStream_t stream) {
    const float* x     = (const float*)d_in[0];
    const int*   ei    = (const int*)d_in[1];
    const int*   batch = (const int*)d_in[2];
    const float* Ws    = (const float*)d_in[3];
    const float* bs    = (const float*)d_in[4];
    const float* Wc    = (const float*)d_in[5];
    const float* bc    = (const float*)d_in[6];
    float* out = (float*)d_out;

    const int* src = ei;            // edge_index[0]
    const int* dst = ei + NEDGES;   // edge_index[1]

    char* ws = (char*)d_ws;
    size_t off = 0;
    auto alloc = [&](size_t bytes) -> void* {
        off = (off + 255) & ~(size_t)255;
        void* p = ws + off;
        off += bytes;
        return p;
    };
    float*    T0       = (float*)alloc(sizeof(float) * (size_t)NNODES * NF);
    float*    T1       = (float*)alloc(sizeof(float) * (size_t)NNODES * NF);
    float*    dinvp    = (float*)alloc(sizeof(float) * NNODES);
    unsigned* cnt      = (unsigned*)alloc(sizeof(unsigned) * NNODES);
    unsigned* cursor   = (unsigned*)alloc(sizeof(unsigned) * NNODES);
    unsigned* rowptr   = (unsigned*)alloc(sizeof(unsigned) * (NNODES + 1));
    unsigned* csr_src  = (unsigned*)alloc(sizeof(unsigned) * NEDGES);
    float*    csr_norm = (float*)alloc(sizeof(float) * NEDGES);
    float*    G        = (float*)alloc(sizeof(float) * NGRAPHS * NF);

    hipMemsetAsync(cnt, 0, sizeof(unsigned) * NNODES, stream);
    hist_kernel<<<(NEDGES + 255) / 256, 256, 0, stream>>>(dst, cnt, NEDGES);
    dinv_kernel<<<(NNODES + 255) / 256, 256, 0, stream>>>(cnt, dinvp, NNODES);
    scan_kernel<<<1, 1024, 0, stream>>>(cnt, rowptr, cursor, NNODES);
    fill_kernel<<<(NEDGES + 255) / 256, 256, 0, stream>>>(src, dst, dinvp, cursor,
                                                          csr_src, csr_norm, NEDGES);

    int gemm_grid = (NNODES + 63) / 64;
    int agg_grid  = (NNODES * 32) / 256;  // 12500, exact

    // layer 0: x -> T0(h) -> T1
    gemm_kernel<<<gemm_grid, 256, 0, stream>>>(x, Ws + 0 * NF * NF, T0, NNODES);
    aggregate_kernel<<<agg_grid, 256, 0, stream>>>(T0, dinvp, rowptr, csr_src, csr_norm,
                                                   bs + 0 * NF, T1, NNODES);
    // layer 1: T1 -> T0(h) -> T1
    gemm_kernel<<<gemm_grid, 256, 0, stream>>>(T1, Ws + 1 * NF * NF, T0, NNODES);
    aggregate_kernel<<<agg_grid, 256, 0, stream>>>(T0, dinvp, rowptr, csr_src, csr_norm,
                                                   bs + 1 * NF, T1, NNODES);
    // layer 2: T1 -> T0(h) -> T1
    gemm_kernel<<<gemm_grid, 256, 0, stream>>>(T1, Ws + 2 * NF * NF, T0, NNODES);
    aggregate_kernel<<<agg_grid, 256, 0, stream>>>(T0, dinvp, rowptr, csr_src, csr_norm,
                                                   bs + 2 * NF, T1, NNODES);

    pool_kernel<<<NGRAPHS, 128, 0, stream>>>(T1, batch, G, NNODES);
    classify_kernel<<<NGRAPHS, 128, 0, stream>>>(G, Wc, bc, out);
}

// Round 2
// 581.224 us; speedup vs baseline: 1.1460x; 1.1460x over previous
//
#include <hip/hip_runtime.h>
#include <float.h>
#include <math.h>

#define NNODES 100000
#define NEDGES 800000
#define NF 128
#define NLAYERS 3
#define NCLASSES 10
#define NGRAPHS 256

#define SCAN_CHUNK 2048  // elements per block in multi-block scan (256 thr x 8)
#define SCAN_NB ((NNODES + SCAN_CHUNK - 1) / SCAN_CHUNK)  // 49

// ---------------- degree histogram (dst occurrences) ----------------
__global__ __launch_bounds__(256) void hist_kernel(const int* __restrict__ dst,
                                                   unsigned* __restrict__ cnt, int E) {
    int i = blockIdx.x * 256 + threadIdx.x;
    if (i < E) atomicAdd(&cnt[dst[i]], 1u);
}

// ---------------- dinv = rsqrt(in_deg + 1)  (self-loop included) ----------------
__global__ __launch_bounds__(256) void dinv_kernel(const unsigned* __restrict__ cnt,
                                                   float* __restrict__ dinv, int N) {
    int i = blockIdx.x * 256 + threadIdx.x;
    if (i < N) dinv[i] = rsqrtf((float)cnt[i] + 1.0f);
}

// ---------------- multi-block exclusive scan: A) block sums ----------------
__global__ __launch_bounds__(256) void scanA_kernel(const unsigned* __restrict__ cnt,
                                                    unsigned* __restrict__ bsum, int N) {
    __shared__ unsigned wsum[4];
    int tid = threadIdx.x, wid = tid >> 6, lane = tid & 63;
    int base = blockIdx.x * SCAN_CHUNK + tid * 8;
    unsigned s = 0;
    if (base < N) {  // N % 8 == 0 -> fully in or fully out
        uint4 a = *(const uint4*)(cnt + base);
        uint4 b = *(const uint4*)(cnt + base + 4);
        s = a.x + a.y + a.z + a.w + b.x + b.y + b.z + b.w;
    }
    #pragma unroll
    for (int off = 32; off >= 1; off >>= 1) s += __shfl_down(s, off, 64);
    if (lane == 0) wsum[wid] = s;
    __syncthreads();
    if (tid == 0) bsum[blockIdx.x] = wsum[0] + wsum[1] + wsum[2] + wsum[3];
}

// ---------------- B) scan the block sums (one wave) ----------------
__global__ __launch_bounds__(64) void scanB_kernel(const unsigned* __restrict__ bsum,
                                                   unsigned* __restrict__ boff,
                                                   unsigned* __restrict__ rowptr_last) {
    int lane = threadIdx.x;
    unsigned v = (lane < SCAN_NB) ? bsum[lane] : 0u;
    unsigned incl = v;
    #pragma unroll
    for (int off = 1; off < 64; off <<= 1) {
        unsigned t = __shfl_up(incl, off, 64);
        if (lane >= off) incl += t;
    }
    if (lane < SCAN_NB) boff[lane] = incl - v;
    if (lane == 63) *rowptr_last = incl;  // total = rowptr[N]
}

// ---------------- C) local rescan + add block offset -> rowptr, cursor ----------------
__global__ __launch_bounds__(256) void scanC_kernel(const unsigned* __restrict__ cnt,
                                                    const unsigned* __restrict__ boff,
                                                    unsigned* __restrict__ rowptr,
                                                    unsigned* __restrict__ cursor, int N) {
    __shared__ unsigned wsum[4];
    int tid = threadIdx.x, wid = tid >> 6, lane = tid & 63;
    int base = blockIdx.x * SCAN_CHUNK + tid * 8;
    unsigned v[8];
    unsigned s = 0;
    bool act = base < N;
    if (act) {
        uint4 a = *(const uint4*)(cnt + base);
        uint4 b = *(const uint4*)(cnt + base + 4);
        v[0] = a.x; v[1] = a.y; v[2] = a.z; v[3] = a.w;
        v[4] = b.x; v[5] = b.y; v[6] = b.z; v[7] = b.w;
        #pragma unroll
        for (int j = 0; j < 8; ++j) s += v[j];
    }
    unsigned incl = s;
    #pragma unroll
    for (int off = 1; off < 64; off <<= 1) {
        unsigned t = __shfl_up(incl, off, 64);
        if (lane >= off) incl += t;
    }
    if (lane == 63) wsum[wid] = incl;
    __syncthreads();
    unsigned woff = 0;
    for (int w = 0; w < 4; ++w) if (w < wid) woff += wsum[w];
    if (act) {
        unsigned run = incl - s + woff + boff[blockIdx.x];
        #pragma unroll
        for (int j = 0; j < 8; ++j) {
            rowptr[base + j] = run;
            cursor[base + j] = run;
            run += v[j];
        }
    }
}

// ---------------- CSR fill: per edge, slot = cursor[dst]++ ----------------
__global__ __launch_bounds__(256) void fill_kernel(const int* __restrict__ src,
                                                   const int* __restrict__ dst,
                                                   const float* __restrict__ dinv,
                                                   unsigned* __restrict__ cursor,
                                                   unsigned* __restrict__ csr_src,
                                                   float* __restrict__ csr_norm, int E) {
    int e = blockIdx.x * 256 + threadIdx.x;
    if (e < E) {
        int s = src[e], d = dst[e];
        unsigned pos = atomicAdd(&cursor[d], 1u);
        csr_src[pos] = (unsigned)s;
        csr_norm[pos] = dinv[s] * dinv[d];
    }
}

// ---------------- H = X @ W   (M x 128) @ (128 x 128), fp32 ----------------
__global__ __launch_bounds__(256) void gemm_kernel(const float* __restrict__ X,
                                                   const float* __restrict__ W,
                                                   float* __restrict__ H, int M) {
    __shared__ float Xl[64][128];   // 32 KB
    __shared__ float Wl[128][64];   // 32 KB (one N-half)
    int tid = threadIdx.x;
    int row0 = blockIdx.x * 64;

    for (int i = tid; i < 64 * 32; i += 256) {
        int r = i >> 5, kv = i & 31;
        float4 v = make_float4(0.f, 0.f, 0.f, 0.f);
        int row = row0 + r;
        if (row < M) v = ((const float4*)(X + (size_t)row * NF))[kv];
        ((float4*)Xl[r])[kv] = v;
    }

    int tc = tid & 15, tr = tid >> 4;
    int c0 = tc * 4, r0 = tr * 4;

    for (int nh = 0; nh < 2; ++nh) {
        __syncthreads();
        for (int i = tid; i < 128 * 16; i += 256) {
            int k = i >> 4, cv = i & 15;
            ((float4*)Wl[k])[cv] = ((const float4*)(W + (size_t)k * NF + nh * 64))[cv];
        }
        __syncthreads();

        float acc[4][4];
        #pragma unroll
        for (int r = 0; r < 4; ++r) { acc[r][0] = 0.f; acc[r][1] = 0.f; acc[r][2] = 0.f; acc[r][3] = 0.f; }

        #pragma unroll 4
        for (int kc = 0; kc < 32; ++kc) {
            int k = kc * 4;
            float4 w0 = *(const float4*)&Wl[k + 0][c0];
            float4 w1 = *(const float4*)&Wl[k + 1][c0];
            float4 w2 = *(const float4*)&Wl[k + 2][c0];
            float4 w3 = *(const float4*)&Wl[k + 3][c0];
            #pragma unroll
            for (int r = 0; r < 4; ++r) {
                float4 xv = *(const float4*)&Xl[r0 + r][k];
                acc[r][0] = fmaf(xv.x, w0.x, fmaf(xv.y, w1.x, fmaf(xv.z, w2.x, fmaf(xv.w, w3.x, acc[r][0]))));
                acc[r][1] = fmaf(xv.x, w0.y, fmaf(xv.y, w1.y, fmaf(xv.z, w2.y, fmaf(xv.w, w3.y, acc[r][1]))));
                acc[r][2] = fmaf(xv.x, w0.z, fmaf(xv.y, w1.z, fmaf(xv.z, w2.z, fmaf(xv.w, w3.z, acc[r][2]))));
                acc[r][3] = fmaf(xv.x, w0.w, fmaf(xv.y, w1.w, fmaf(xv.z, w2.w, fmaf(xv.w, w3.w, acc[r][3]))));
            }
        }
        #pragma unroll
        for (int r = 0; r < 4; ++r) {
            int row = row0 + r0 + r;
            if (row < M)
                *(float4*)&H[(size_t)row * NF + nh * 64 + c0] =
                    make_float4(acc[r][0], acc[r][1], acc[r][2], acc[r][3]);
        }
    }
}

// ---------------- aggregate: Xout = ELU( dinv^2*H[i] + sum_csr norm*H[src] + bias ) ----------------
__global__ __launch_bounds__(256) void aggregate_kernel(const float* __restrict__ H,
                                                        const float* __restrict__ dinv,
                                                        const unsigned* __restrict__ rowptr,
                                                        const unsigned* __restrict__ csr_src,
                                                        const float* __restrict__ csr_norm,
                                                        const float* __restrict__ bias,
                                                        float* __restrict__ Xout, int N) {
    int gid = blockIdx.x * 256 + threadIdx.x;
    int node = gid >> 5;
    int lane = gid & 31;
    if (node >= N) return;
    float di = dinv[node];
    float sl = di * di;
    float4 b = ((const float4*)bias)[lane];
    float4 hv = ((const float4*)(H + (size_t)node * NF))[lane];
    float ax = fmaf(hv.x, sl, b.x);
    float ay = fmaf(hv.y, sl, b.y);
    float az = fmaf(hv.z, sl, b.z);
    float aw = fmaf(hv.w, sl, b.w);
    unsigned beg = rowptr[node], end = rowptr[node + 1];
    for (unsigned e = beg; e < end; ++e) {
        unsigned s = csr_src[e];
        float nm = csr_norm[e];
        float4 h2 = ((const float4*)(H + (size_t)s * NF))[lane];
        ax = fmaf(h2.x, nm, ax);
        ay = fmaf(h2.y, nm, ay);
        az = fmaf(h2.z, nm, az);
        aw = fmaf(h2.w, nm, aw);
    }
    ax = ax > 0.f ? ax : expm1f(ax);
    ay = ay > 0.f ? ay : expm1f(ay);
    az = az > 0.f ? az : expm1f(az);
    aw = aw > 0.f ? aw : expm1f(aw);
    ((float4*)(Xout + (size_t)node * NF))[lane] = make_float4(ax, ay, az, aw);
}

// ---------------- global max pool per graph (batch is sorted) ----------------
__global__ __launch_bounds__(128) void pool_kernel(const float* __restrict__ X,
                                                   const int* __restrict__ batch,
                                                   float* __restrict__ G, int N) {
    int g = blockIdx.x;
    int tid = threadIdx.x;
    int lo = 0, hi = N;
    while (lo < hi) { int mid = (lo + hi) >> 1; if (batch[mid] < g) lo = mid + 1; else hi = mid; }
    int beg = lo;
    hi = N;
    while (lo < hi) { int mid = (lo + hi) >> 1; if (batch[mid] < g + 1) lo = mid + 1; else hi = mid; }
    int end = lo;
    float m = -FLT_MAX;
    for (int r = beg; r < end; ++r) m = fmaxf(m, X[(size_t)r * NF + tid]);
    G[g * NF + tid] = m;
}

// ---------------- classifier: softmax(G @ Wc + bc) ----------------
__global__ __launch_bounds__(128) void classify_kernel(const float* __restrict__ G,
                                                       const float* __restrict__ Wc,
                                                       const float* __restrict__ bc,
                                                       float* __restrict__ out) {
    __shared__ float gr[NF];
    __shared__ float lg[NCLASSES];
    int g = blockIdx.x;
    int tid = threadIdx.x;
    gr[tid] = G[g * NF + tid];
    __syncthreads();
    if (tid < NCLASSES) {
        float s = bc[tid];
        for (int k = 0; k < NF; ++k) s = fmaf(gr[k], Wc[k * NCLASSES + tid], s);
        lg[tid] = s;
    }
    __syncthreads();
    if (tid == 0) {
        float m = lg[0];
        #pragma unroll
        for (int c = 1; c < NCLASSES; ++c) m = fmaxf(m, lg[c]);
        float e[NCLASSES];
        float sum = 0.f;
        #pragma unroll
        for (int c = 0; c < NCLASSES; ++c) { e[c] = expf(lg[c] - m); sum += e[c]; }
        #pragma unroll
        for (int c = 0; c < NCLASSES; ++c) out[g * NCLASSES + c] = e[c] / sum;
    }
}

extern "C" void kernel_launch(void* const* d_in, const int* in_sizes, int n_in,
                              void* d_out, int out_size, void* d_ws, size_t ws_size,
                              hipStream_t stream) {
    const float* x     = (const float*)d_in[0];
    const int*   ei    = (const int*)d_in[1];
    const int*   batch = (const int*)d_in[2];
    const float* Ws    = (const float*)d_in[3];
    const float* bs    = (const float*)d_in[4];
    const float* Wc    = (const float*)d_in[5];
    const float* bc    = (const float*)d_in[6];
    float* out = (float*)d_out;

    const int* src = ei;            // edge_index[0]
    const int* dst = ei + NEDGES;   // edge_index[1]

    char* ws = (char*)d_ws;
    size_t off = 0;
    auto alloc = [&](size_t bytes) -> void* {
        off = (off + 255) & ~(size_t)255;
        void* p = ws + off;
        off += bytes;
        return p;
    };
    float*    T0       = (float*)alloc(sizeof(float) * (size_t)NNODES * NF);
    float*    T1       = (float*)alloc(sizeof(float) * (size_t)NNODES * NF);
    float*    dinvp    = (float*)alloc(sizeof(float) * NNODES);
    unsigned* cnt      = (unsigned*)alloc(sizeof(unsigned) * NNODES);
    unsigned* cursor   = (unsigned*)alloc(sizeof(unsigned) * NNODES);
    unsigned* rowptr   = (unsigned*)alloc(sizeof(unsigned) * (NNODES + 1));
    unsigned* csr_src  = (unsigned*)alloc(sizeof(unsigned) * NEDGES);
    float*    csr_norm = (float*)alloc(sizeof(float) * NEDGES);
    unsigned* bsum     = (unsigned*)alloc(sizeof(unsigned) * SCAN_NB);
    unsigned* boff     = (unsigned*)alloc(sizeof(unsigned) * SCAN_NB);
    float*    G        = (float*)alloc(sizeof(float) * NGRAPHS * NF);

    hipMemsetAsync(cnt, 0, sizeof(unsigned) * NNODES, stream);
    hist_kernel<<<(NEDGES + 255) / 256, 256, 0, stream>>>(dst, cnt, NEDGES);
    dinv_kernel<<<(NNODES + 255) / 256, 256, 0, stream>>>(cnt, dinvp, NNODES);
    scanA_kernel<<<SCAN_NB, 256, 0, stream>>>(cnt, bsum, NNODES);
    scanB_kernel<<<1, 64, 0, stream>>>(bsum, boff, rowptr + NNODES);
    scanC_kernel<<<SCAN_NB, 256, 0, stream>>>(cnt, boff, rowptr, cursor, NNODES);
    fill_kernel<<<(NEDGES + 255) / 256, 256, 0, stream>>>(src, dst, dinvp, cursor,
                                                          csr_src, csr_norm, NEDGES);

    int gemm_grid = (NNODES + 63) / 64;
    int agg_grid  = (NNODES * 32) / 256;  // 12500, exact

    gemm_kernel<<<gemm_grid, 256, 0, stream>>>(x, Ws + 0 * NF * NF, T0, NNODES);
    aggregate_kernel<<<agg_grid, 256, 0, stream>>>(T0, dinvp, rowptr, csr_src, csr_norm,
                                                   bs + 0 * NF, T1, NNODES);
    gemm_kernel<<<gemm_grid, 256, 0, stream>>>(T1, Ws + 1 * NF * NF, T0, NNODES);
    aggregate_kernel<<<agg_grid, 256, 0, stream>>>(T0, dinvp, rowptr, csr_src, csr_norm,
                                                   bs + 1 * NF, T1, NNODES);
    gemm_kernel<<<gemm_grid, 256, 0, stream>>>(T1, Ws + 2 * NF * NF, T0, NNODES);
    aggregate_kernel<<<agg_grid, 256, 0, stream>>>(T0, dinvp, rowptr, csr_src, csr_norm,
                                                   bs + 2 * NF, T1, NNODES);

    pool_kernel<<<NGRAPHS, 128, 0, stream>>>(T1, batch, G, NNODES);
    classify_kernel<<<NGRAPHS, 128, 0, stream>>>(G, Wc, bc, out);
}

// Round 3
// 363.038 us; speedup vs baseline: 1.8347x; 1.6010x over previous
//
#include <hip/hip_runtime.h>
#include <float.h>
#include <math.h>

#define NNODES 100000
#define NEDGES 800000
#define NF 128
#define NCLASSES 10
#define NGRAPHS 256

#define SCAN_CHUNK 2048
#define SCAN_NB ((NNODES + SCAN_CHUNK - 1) / SCAN_CHUNK)  // 49

typedef __attribute__((ext_vector_type(8))) short bf16x8;
typedef __attribute__((ext_vector_type(4))) float f32x4;

__device__ inline ushort f2bf(float f) {  // fp32 -> bf16 RNE
    unsigned u = __float_as_uint(f);
    u = u + 0x7FFFu + ((u >> 16) & 1u);
    return (ushort)(u >> 16);
}
__device__ inline float b2f(ushort h) {
    return __uint_as_float(((unsigned)h) << 16);
}

// ---------------- degree histogram (dst occurrences) ----------------
__global__ __launch_bounds__(256) void hist_kernel(const int* __restrict__ dst,
                                                   unsigned* __restrict__ cnt, int E) {
    int i = blockIdx.x * 256 + threadIdx.x;
    if (i < E) atomicAdd(&cnt[dst[i]], 1u);
}

// ---------------- dinv = rsqrt(in_deg + 1) ----------------
__global__ __launch_bounds__(256) void dinv_kernel(const unsigned* __restrict__ cnt,
                                                   float* __restrict__ dinv, int N) {
    int i = blockIdx.x * 256 + threadIdx.x;
    if (i < N) dinv[i] = rsqrtf((float)cnt[i] + 1.0f);
}

// ---------------- multi-block exclusive scan ----------------
__global__ __launch_bounds__(256) void scanA_kernel(const unsigned* __restrict__ cnt,
                                                    unsigned* __restrict__ bsum, int N) {
    __shared__ unsigned wsum[4];
    int tid = threadIdx.x, wid = tid >> 6, lane = tid & 63;
    int base = blockIdx.x * SCAN_CHUNK + tid * 8;
    unsigned s = 0;
    if (base < N) {
        uint4 a = *(const uint4*)(cnt + base);
        uint4 b = *(const uint4*)(cnt + base + 4);
        s = a.x + a.y + a.z + a.w + b.x + b.y + b.z + b.w;
    }
    #pragma unroll
    for (int off = 32; off >= 1; off >>= 1) s += __shfl_down(s, off, 64);
    if (lane == 0) wsum[wid] = s;
    __syncthreads();
    if (tid == 0) bsum[blockIdx.x] = wsum[0] + wsum[1] + wsum[2] + wsum[3];
}

__global__ __launch_bounds__(64) void scanB_kernel(const unsigned* __restrict__ bsum,
                                                   unsigned* __restrict__ boff,
                                                   unsigned* __restrict__ rowptr_last) {
    int lane = threadIdx.x;
    unsigned v = (lane < SCAN_NB) ? bsum[lane] : 0u;
    unsigned incl = v;
    #pragma unroll
    for (int off = 1; off < 64; off <<= 1) {
        unsigned t = __shfl_up(incl, off, 64);
        if (lane >= off) incl += t;
    }
    if (lane < SCAN_NB) boff[lane] = incl - v;
    if (lane == 63) *rowptr_last = incl;
}

__global__ __launch_bounds__(256) void scanC_kernel(const unsigned* __restrict__ cnt,
                                                    const unsigned* __restrict__ boff,
                                                    unsigned* __restrict__ rowptr,
                                                    unsigned* __restrict__ cursor, int N) {
    __shared__ unsigned wsum[4];
    int tid = threadIdx.x, wid = tid >> 6, lane = tid & 63;
    int base = blockIdx.x * SCAN_CHUNK + tid * 8;
    unsigned v[8];
    unsigned s = 0;
    bool act = base < N;
    if (act) {
        uint4 a = *(const uint4*)(cnt + base);
        uint4 b = *(const uint4*)(cnt + base + 4);
        v[0] = a.x; v[1] = a.y; v[2] = a.z; v[3] = a.w;
        v[4] = b.x; v[5] = b.y; v[6] = b.z; v[7] = b.w;
        #pragma unroll
        for (int j = 0; j < 8; ++j) s += v[j];
    }
    unsigned incl = s;
    #pragma unroll
    for (int off = 1; off < 64; off <<= 1) {
        unsigned t = __shfl_up(incl, off, 64);
        if (lane >= off) incl += t;
    }
    if (lane == 63) wsum[wid] = incl;
    __syncthreads();
    unsigned woff = 0;
    for (int w = 0; w < 4; ++w) if (w < wid) woff += wsum[w];
    if (act) {
        unsigned run = incl - s + woff + boff[blockIdx.x];
        #pragma unroll
        for (int j = 0; j < 8; ++j) {
            rowptr[base + j] = run;
            cursor[base + j] = run;
            run += v[j];
        }
    }
}

// ---------------- CSR fill: packed (src, norm) ----------------
__global__ __launch_bounds__(256) void fill_kernel(const int* __restrict__ src,
                                                   const int* __restrict__ dst,
                                                   const float* __restrict__ dinv,
                                                   unsigned* __restrict__ cursor,
                                                   uint2* __restrict__ csr, int E) {
    int e = blockIdx.x * 256 + threadIdx.x;
    if (e < E) {
        int s = src[e], d = dst[e];
        unsigned pos = atomicAdd(&cursor[d], 1u);
        uint2 v;
        v.x = (unsigned)s;
        v.y = __float_as_uint(dinv[s] * dinv[d]);
        csr[pos] = v;
    }
}

// ---------------- W -> lane-ordered bf16 MFMA fragments ----------------
// Wf[layer][ntile(8)][kstep(4)][lane(64)][i(8)] = W[k][n],
//   k = kstep*32 + (lane>>4)*8 + i, n = ntile*16 + (lane&15)
__global__ __launch_bounds__(256) void wprep_kernel(const float* __restrict__ Ws,
                                                    short* __restrict__ Wf) {
    int l = blockIdx.x;
    for (int idx = threadIdx.x; idx < 16384; idx += 256) {
        int i = idx & 7;
        int lane = (idx >> 3) & 63;
        int ns = idx >> 9;
        int s = ns & 3, nt = ns >> 2;
        int k = s * 32 + (lane >> 4) * 8 + i;
        int n = nt * 16 + (lane & 15);
        Wf[l * 16384 + idx] = (short)f2bf(Ws[l * 16384 + k * NF + n]);
    }
}

// ---------------- H = X @ W via bf16 MFMA; output bf16 ----------------
// block: 256 thr = 4 waves, 128 rows x 128 cols. wave: 32 rows.
template<bool L0>
__global__ __launch_bounds__(256) void gemm_mfma_kernel(const void* __restrict__ Xin,
                                                        const short* __restrict__ Wf,
                                                        ushort* __restrict__ Hb, int M) {
    __shared__ short Wl[16384];  // 32 KB: all B fragments, lane-ordered
    int tid = threadIdx.x;
    for (int i = tid; i < 2048; i += 256)
        ((float4*)Wl)[i] = ((const float4*)Wf)[i];

    int wave = tid >> 6, lane = tid & 63;
    int r = lane & 15, kg = lane >> 4;
    int rowbase = blockIdx.x * 128 + wave * 32;

    bf16x8 afrag[2][4];
    #pragma unroll
    for (int t = 0; t < 2; ++t) {
        #pragma unroll
        for (int s = 0; s < 4; ++s) {
            int row = rowbase + t * 16 + r;
            if (row > M - 1) row = M - 1;
            if (L0) {
                const float* p = (const float*)Xin + (size_t)row * NF + s * 32 + kg * 8;
                float4 u0 = *(const float4*)p;
                float4 u1 = *(const float4*)(p + 4);
                bf16x8 a;
                a[0] = (short)f2bf(u0.x); a[1] = (short)f2bf(u0.y);
                a[2] = (short)f2bf(u0.z); a[3] = (short)f2bf(u0.w);
                a[4] = (short)f2bf(u1.x); a[5] = (short)f2bf(u1.y);
                a[6] = (short)f2bf(u1.z); a[7] = (short)f2bf(u1.w);
                afrag[t][s] = a;
            } else {
                afrag[t][s] = *(const bf16x8*)((const ushort*)Xin + (size_t)row * NF + s * 32 + kg * 8);
            }
        }
    }

    f32x4 acc[2][8];
    #pragma unroll
    for (int t = 0; t < 2; ++t)
        #pragma unroll
        for (int n = 0; n < 8; ++n)
            acc[t][n] = (f32x4){0.f, 0.f, 0.f, 0.f};

    __syncthreads();
    const bf16x8* WL = (const bf16x8*)Wl;
    #pragma unroll
    for (int s = 0; s < 4; ++s) {
        #pragma unroll
        for (int n = 0; n < 8; ++n) {
            bf16x8 b = WL[(n * 4 + s) * 64 + lane];
            acc[0][n] = __builtin_amdgcn_mfma_f32_16x16x32_bf16(afrag[0][s], b, acc[0][n], 0, 0, 0);
            acc[1][n] = __builtin_amdgcn_mfma_f32_16x16x32_bf16(afrag[1][s], b, acc[1][n], 0, 0, 0);
        }
    }

    int r4 = kg * 4;
    #pragma unroll
    for (int t = 0; t < 2; ++t) {
        #pragma unroll
        for (int n = 0; n < 8; ++n) {
            #pragma unroll
            for (int q = 0; q < 4; ++q) {
                int row = rowbase + t * 16 + r4 + q;
                if (row < M) Hb[(size_t)row * NF + n * 16 + r] = f2bf(acc[t][n][q]);
            }
        }
    }
}

// ---------------- aggregate: bf16 gather, fp32 math, bf16 out ----------------
__global__ __launch_bounds__(256) void aggregate_kernel(const ushort* __restrict__ Hb,
                                                        const float* __restrict__ dinv,
                                                        const unsigned* __restrict__ rowptr,
                                                        const uint2* __restrict__ csr,
                                                        const float* __restrict__ bias,
                                                        ushort* __restrict__ Xout, int N) {
    int gid = blockIdx.x * 256 + threadIdx.x;
    int node = gid >> 5;
    int lane = gid & 31;
    if (node >= N) return;
    float di = dinv[node];
    float sl = di * di;
    float4 b = ((const float4*)bias)[lane];
    ushort4 hv = *(const ushort4*)(Hb + (size_t)node * NF + lane * 4);
    float ax = fmaf(b2f(hv.x), sl, b.x);
    float ay = fmaf(b2f(hv.y), sl, b.y);
    float az = fmaf(b2f(hv.z), sl, b.z);
    float aw = fmaf(b2f(hv.w), sl, b.w);
    unsigned e = rowptr[node], end = rowptr[node + 1];
    for (; e + 4 <= end; e += 4) {
        uint2 m0 = csr[e + 0], m1 = csr[e + 1], m2 = csr[e + 2], m3 = csr[e + 3];
        ushort4 g0 = *(const ushort4*)(Hb + (size_t)m0.x * NF + lane * 4);
        ushort4 g1 = *(const ushort4*)(Hb + (size_t)m1.x * NF + lane * 4);
        ushort4 g2 = *(const ushort4*)(Hb + (size_t)m2.x * NF + lane * 4);
        ushort4 g3 = *(const ushort4*)(Hb + (size_t)m3.x * NF + lane * 4);
        float n0 = __uint_as_float(m0.y), n1 = __uint_as_float(m1.y);
        float n2 = __uint_as_float(m2.y), n3 = __uint_as_float(m3.y);
        ax = fmaf(b2f(g0.x), n0, ax); ay = fmaf(b2f(g0.y), n0, ay);
        az = fmaf(b2f(g0.z), n0, az); aw = fmaf(b2f(g0.w), n0, aw);
        ax = fmaf(b2f(g1.x), n1, ax); ay = fmaf(b2f(g1.y), n1, ay);
        az = fmaf(b2f(g1.z), n1, az); aw = fmaf(b2f(g1.w), n1, aw);
        ax = fmaf(b2f(g2.x), n2, ax); ay = fmaf(b2f(g2.y), n2, ay);
        az = fmaf(b2f(g2.z), n2, az); aw = fmaf(b2f(g2.w), n2, aw);
        ax = fmaf(b2f(g3.x), n3, ax); ay = fmaf(b2f(g3.y), n3, ay);
        az = fmaf(b2f(g3.z), n3, az); aw = fmaf(b2f(g3.w), n3, aw);
    }
    for (; e < end; ++e) {
        uint2 m = csr[e];
        ushort4 g = *(const ushort4*)(Hb + (size_t)m.x * NF + lane * 4);
        float nm = __uint_as_float(m.y);
        ax = fmaf(b2f(g.x), nm, ax); ay = fmaf(b2f(g.y), nm, ay);
        az = fmaf(b2f(g.z), nm, az); aw = fmaf(b2f(g.w), nm, aw);
    }
    ax = ax > 0.f ? ax : expm1f(ax);
    ay = ay > 0.f ? ay : expm1f(ay);
    az = az > 0.f ? az : expm1f(az);
    aw = aw > 0.f ? aw : expm1f(aw);
    ushort4 o;
    o.x = f2bf(ax); o.y = f2bf(ay); o.z = f2bf(az); o.w = f2bf(aw);
    *(ushort4*)(Xout + (size_t)node * NF + lane * 4) = o;
}

// ---------------- global max pool per graph (batch sorted), bf16 in ----------------
__global__ __launch_bounds__(128) void pool_kernel(const ushort* __restrict__ X,
                                                   const int* __restrict__ batch,
                                                   float* __restrict__ G, int N) {
    int g = blockIdx.x;
    int tid = threadIdx.x;
    int lo = 0, hi = N;
    while (lo < hi) { int mid = (lo + hi) >> 1; if (batch[mid] < g) lo = mid + 1; else hi = mid; }
    int beg = lo;
    hi = N;
    while (lo < hi) { int mid = (lo + hi) >> 1; if (batch[mid] < g + 1) lo = mid + 1; else hi = mid; }
    int end = lo;
    float m = -FLT_MAX;
    for (int r = beg; r < end; ++r) m = fmaxf(m, b2f(X[(size_t)r * NF + tid]));
    G[g * NF + tid] = m;
}

// ---------------- classifier: softmax(G @ Wc + bc), fp32 ----------------
__global__ __launch_bounds__(128) void classify_kernel(const float* __restrict__ G,
                                                       const float* __restrict__ Wc,
                                                       const float* __restrict__ bc,
                                                       float* __restrict__ out) {
    __shared__ float gr[NF];
    __shared__ float lg[NCLASSES];
    int g = blockIdx.x;
    int tid = threadIdx.x;
    gr[tid] = G[g * NF + tid];
    __syncthreads();
    if (tid < NCLASSES) {
        float s = bc[tid];
        for (int k = 0; k < NF; ++k) s = fmaf(gr[k], Wc[k * NCLASSES + tid], s);
        lg[tid] = s;
    }
    __syncthreads();
    if (tid == 0) {
        float m = lg[0];
        #pragma unroll
        for (int c = 1; c < NCLASSES; ++c) m = fmaxf(m, lg[c]);
        float e[NCLASSES];
        float sum = 0.f;
        #pragma unroll
        for (int c = 0; c < NCLASSES; ++c) { e[c] = expf(lg[c] - m); sum += e[c]; }
        #pragma unroll
        for (int c = 0; c < NCLASSES; ++c) out[g * NCLASSES + c] = e[c] / sum;
    }
}

extern "C" void kernel_launch(void* const* d_in, const int* in_sizes, int n_in,
                              void* d_out, int out_size, void* d_ws, size_t ws_size,
                              hipStream_t stream) {
    const float* x     = (const float*)d_in[0];
    const int*   ei    = (const int*)d_in[1];
    const int*   batch = (const int*)d_in[2];
    const float* Ws    = (const float*)d_in[3];
    const float* bs    = (const float*)d_in[4];
    const float* Wc    = (const float*)d_in[5];
    const float* bc    = (const float*)d_in[6];
    float* out = (float*)d_out;

    const int* src = ei;
    const int* dst = ei + NEDGES;

    char* ws = (char*)d_ws;
    size_t off = 0;
    auto alloc = [&](size_t bytes) -> void* {
        off = (off + 255) & ~(size_t)255;
        void* p = ws + off;
        off += bytes;
        return p;
    };
    ushort*   B0     = (ushort*)alloc(sizeof(ushort) * (size_t)NNODES * NF);
    ushort*   B1     = (ushort*)alloc(sizeof(ushort) * (size_t)NNODES * NF);
    ushort*   Hb     = (ushort*)alloc(sizeof(ushort) * (size_t)NNODES * NF);
    float*    dinvp  = (float*)alloc(sizeof(float) * NNODES);
    unsigned* cnt    = (unsigned*)alloc(sizeof(unsigned) * NNODES);
    unsigned* cursor = (unsigned*)alloc(sizeof(unsigned) * NNODES);
    unsigned* rowptr = (unsigned*)alloc(sizeof(unsigned) * (NNODES + 1));
    uint2*    csr    = (uint2*)alloc(sizeof(uint2) * NEDGES);
    unsigned* bsum   = (unsigned*)alloc(sizeof(unsigned) * SCAN_NB);
    unsigned* boff   = (unsigned*)alloc(sizeof(unsigned) * SCAN_NB);
    short*    Wf     = (short*)alloc(sizeof(short) * 3 * 16384);
    float*    G      = (float*)alloc(sizeof(float) * NGRAPHS * NF);

    hipMemsetAsync(cnt, 0, sizeof(unsigned) * NNODES, stream);
    wprep_kernel<<<3, 256, 0, stream>>>(Ws, Wf);
    hist_kernel<<<(NEDGES + 255) / 256, 256, 0, stream>>>(dst, cnt, NEDGES);
    dinv_kernel<<<(NNODES + 255) / 256, 256, 0, stream>>>(cnt, dinvp, NNODES);
    scanA_kernel<<<SCAN_NB, 256, 0, stream>>>(cnt, bsum, NNODES);
    scanB_kernel<<<1, 64, 0, stream>>>(bsum, boff, rowptr + NNODES);
    scanC_kernel<<<SCAN_NB, 256, 0, stream>>>(cnt, boff, rowptr, cursor, NNODES);
    fill_kernel<<<(NEDGES + 255) / 256, 256, 0, stream>>>(src, dst, dinvp, cursor, csr, NEDGES);

    int gemm_grid = (NNODES + 127) / 128;   // 782
    int agg_grid  = (NNODES * 32) / 256;    // 12500 exact

    // layer 0: x(fp32) -> Hb -> B1
    gemm_mfma_kernel<true><<<gemm_grid, 256, 0, stream>>>(x, Wf + 0 * 16384, Hb, NNODES);
    aggregate_kernel<<<agg_grid, 256, 0, stream>>>(Hb, dinvp, rowptr, csr, bs + 0 * NF, B1, NNODES);
    // layer 1: B1 -> Hb -> B0
    gemm_mfma_kernel<false><<<gemm_grid, 256, 0, stream>>>(B1, Wf + 1 * 16384, Hb, NNODES);
    aggregate_kernel<<<agg_grid, 256, 0, stream>>>(Hb, dinvp, rowptr, csr, bs + 1 * NF, B0, NNODES);
    // layer 2: B0 -> Hb -> B1
    gemm_mfma_kernel<false><<<gemm_grid, 256, 0, stream>>>(B0, Wf + 2 * 16384, Hb, NNODES);
    aggregate_kernel<<<agg_grid, 256, 0, stream>>>(Hb, dinvp, rowptr, csr, bs + 2 * NF, B1, NNODES);

    pool_kernel<<<NGRAPHS, 128, 0, stream>>>(B1, batch, G, NNODES);
    classify_kernel<<<NGRAPHS, 128, 0, stream>>>(G, Wc, bc, out);
}

// Round 4
// 317.112 us; speedup vs baseline: 2.1004x; 1.1448x over previous
//
#include <hip/hip_runtime.h>
#include <float.h>
#include <math.h>

#define NNODES 100000
#define NEDGES 800000
#define NF 128
#define NCLASSES 10
#define NGRAPHS 256

#define SCAN_CHUNK 2048
#define SCAN_NB ((NNODES + SCAN_CHUNK - 1) / SCAN_CHUNK)  // 49

typedef __attribute__((ext_vector_type(8))) short bf16x8;
typedef __attribute__((ext_vector_type(4))) float f32x4;

__device__ inline ushort f2bf(float f) {  // fp32 -> bf16 RNE
    unsigned u = __float_as_uint(f);
    u = u + 0x7FFFu + ((u >> 16) & 1u);
    return (ushort)(u >> 16);
}
__device__ inline float b2f(ushort h) {
    return __uint_as_float(((unsigned)h) << 16);
}
// monotone fp32<->uint encoding: uint max order == float max order
__device__ inline unsigned fenc(float f) {
    unsigned u = __float_as_uint(f);
    return ((int)u < 0) ? ~u : (u | 0x80000000u);
}
__device__ inline float fdec(unsigned s) {
    return (s & 0x80000000u) ? __uint_as_float(s ^ 0x80000000u) : __uint_as_float(~s);
}

// ---------------- degree histogram (dst occurrences) ----------------
__global__ __launch_bounds__(256) void hist_kernel(const int* __restrict__ dst,
                                                   unsigned* __restrict__ cnt, int E) {
    int i = blockIdx.x * 256 + threadIdx.x;
    if (i < E) atomicAdd(&cnt[dst[i]], 1u);
}

// ---------------- dinv = rsqrt(in_deg + 1) ----------------
__global__ __launch_bounds__(256) void dinv_kernel(const unsigned* __restrict__ cnt,
                                                   float* __restrict__ dinv, int N) {
    int i = blockIdx.x * 256 + threadIdx.x;
    if (i < N) dinv[i] = rsqrtf((float)cnt[i] + 1.0f);
}

// ---------------- multi-block exclusive scan ----------------
__global__ __launch_bounds__(256) void scanA_kernel(const unsigned* __restrict__ cnt,
                                                    unsigned* __restrict__ bsum, int N) {
    __shared__ unsigned wsum[4];
    int tid = threadIdx.x, wid = tid >> 6, lane = tid & 63;
    int base = blockIdx.x * SCAN_CHUNK + tid * 8;
    unsigned s = 0;
    if (base < N) {
        uint4 a = *(const uint4*)(cnt + base);
        uint4 b = *(const uint4*)(cnt + base + 4);
        s = a.x + a.y + a.z + a.w + b.x + b.y + b.z + b.w;
    }
    #pragma unroll
    for (int off = 32; off >= 1; off >>= 1) s += __shfl_down(s, off, 64);
    if (lane == 0) wsum[wid] = s;
    __syncthreads();
    if (tid == 0) bsum[blockIdx.x] = wsum[0] + wsum[1] + wsum[2] + wsum[3];
}

__global__ __launch_bounds__(64) void scanB_kernel(const unsigned* __restrict__ bsum,
                                                   unsigned* __restrict__ boff,
                                                   unsigned* __restrict__ rowptr_last) {
    int lane = threadIdx.x;
    unsigned v = (lane < SCAN_NB) ? bsum[lane] : 0u;
    unsigned incl = v;
    #pragma unroll
    for (int off = 1; off < 64; off <<= 1) {
        unsigned t = __shfl_up(incl, off, 64);
        if (lane >= off) incl += t;
    }
    if (lane < SCAN_NB) boff[lane] = incl - v;
    if (lane == 63) *rowptr_last = incl;
}

__global__ __launch_bounds__(256) void scanC_kernel(const unsigned* __restrict__ cnt,
                                                    const unsigned* __restrict__ boff,
                                                    unsigned* __restrict__ rowptr,
                                                    unsigned* __restrict__ cursor, int N) {
    __shared__ unsigned wsum[4];
    int tid = threadIdx.x, wid = tid >> 6, lane = tid & 63;
    int base = blockIdx.x * SCAN_CHUNK + tid * 8;
    unsigned v[8];
    unsigned s = 0;
    bool act = base < N;
    if (act) {
        uint4 a = *(const uint4*)(cnt + base);
        uint4 b = *(const uint4*)(cnt + base + 4);
        v[0] = a.x; v[1] = a.y; v[2] = a.z; v[3] = a.w;
        v[4] = b.x; v[5] = b.y; v[6] = b.z; v[7] = b.w;
        #pragma unroll
        for (int j = 0; j < 8; ++j) s += v[j];
    }
    unsigned incl = s;
    #pragma unroll
    for (int off = 1; off < 64; off <<= 1) {
        unsigned t = __shfl_up(incl, off, 64);
        if (lane >= off) incl += t;
    }
    if (lane == 63) wsum[wid] = incl;
    __syncthreads();
    unsigned woff = 0;
    for (int w = 0; w < 4; ++w) if (w < wid) woff += wsum[w];
    if (act) {
        unsigned run = incl - s + woff + boff[blockIdx.x];
        #pragma unroll
        for (int j = 0; j < 8; ++j) {
            rowptr[base + j] = run;
            cursor[base + j] = run;
            run += v[j];
        }
    }
}

// ---------------- CSR fill: packed (src, norm) ----------------
__global__ __launch_bounds__(256) void fill_kernel(const int* __restrict__ src,
                                                   const int* __restrict__ dst,
                                                   const float* __restrict__ dinv,
                                                   unsigned* __restrict__ cursor,
                                                   uint2* __restrict__ csr, int E) {
    int e = blockIdx.x * 256 + threadIdx.x;
    if (e < E) {
        int s = src[e], d = dst[e];
        unsigned pos = atomicAdd(&cursor[d], 1u);
        uint2 v;
        v.x = (unsigned)s;
        v.y = __float_as_uint(dinv[s] * dinv[d]);
        csr[pos] = v;
    }
}

// ---------------- W -> lane-ordered bf16 MFMA fragments ----------------
__global__ __launch_bounds__(256) void wprep_kernel(const float* __restrict__ Ws,
                                                    short* __restrict__ Wf) {
    int l = blockIdx.x;
    for (int idx = threadIdx.x; idx < 16384; idx += 256) {
        int i = idx & 7;
        int lane = (idx >> 3) & 63;
        int ns = idx >> 9;
        int s = ns & 3, nt = ns >> 2;
        int k = s * 32 + (lane >> 4) * 8 + i;
        int n = nt * 16 + (lane & 15);
        Wf[l * 16384 + idx] = (short)f2bf(Ws[l * 16384 + k * NF + n]);
    }
}

// ---------------- H = X @ W via bf16 MFMA; output bf16 ----------------
template<bool L0>
__global__ __launch_bounds__(256) void gemm_mfma_kernel(const void* __restrict__ Xin,
                                                        const short* __restrict__ Wf,
                                                        ushort* __restrict__ Hb, int M) {
    __shared__ short Wl[16384];
    int tid = threadIdx.x;
    for (int i = tid; i < 2048; i += 256)
        ((float4*)Wl)[i] = ((const float4*)Wf)[i];

    int wave = tid >> 6, lane = tid & 63;
    int r = lane & 15, kg = lane >> 4;
    int rowbase = blockIdx.x * 128 + wave * 32;

    bf16x8 afrag[2][4];
    #pragma unroll
    for (int t = 0; t < 2; ++t) {
        #pragma unroll
        for (int s = 0; s < 4; ++s) {
            int row = rowbase + t * 16 + r;
            if (row > M - 1) row = M - 1;
            if (L0) {
                const float* p = (const float*)Xin + (size_t)row * NF + s * 32 + kg * 8;
                float4 u0 = *(const float4*)p;
                float4 u1 = *(const float4*)(p + 4);
                bf16x8 a;
                a[0] = (short)f2bf(u0.x); a[1] = (short)f2bf(u0.y);
                a[2] = (short)f2bf(u0.z); a[3] = (short)f2bf(u0.w);
                a[4] = (short)f2bf(u1.x); a[5] = (short)f2bf(u1.y);
                a[6] = (short)f2bf(u1.z); a[7] = (short)f2bf(u1.w);
                afrag[t][s] = a;
            } else {
                afrag[t][s] = *(const bf16x8*)((const ushort*)Xin + (size_t)row * NF + s * 32 + kg * 8);
            }
        }
    }

    f32x4 acc[2][8];
    #pragma unroll
    for (int t = 0; t < 2; ++t)
        #pragma unroll
        for (int n = 0; n < 8; ++n)
            acc[t][n] = (f32x4){0.f, 0.f, 0.f, 0.f};

    __syncthreads();
    const bf16x8* WL = (const bf16x8*)Wl;
    #pragma unroll
    for (int s = 0; s < 4; ++s) {
        #pragma unroll
        for (int n = 0; n < 8; ++n) {
            bf16x8 b = WL[(n * 4 + s) * 64 + lane];
            acc[0][n] = __builtin_amdgcn_mfma_f32_16x16x32_bf16(afrag[0][s], b, acc[0][n], 0, 0, 0);
            acc[1][n] = __builtin_amdgcn_mfma_f32_16x16x32_bf16(afrag[1][s], b, acc[1][n], 0, 0, 0);
        }
    }

    int r4 = kg * 4;
    #pragma unroll
    for (int t = 0; t < 2; ++t) {
        #pragma unroll
        for (int n = 0; n < 8; ++n) {
            #pragma unroll
            for (int q = 0; q < 4; ++q) {
                int row = rowbase + t * 16 + r4 + q;
                if (row < M) Hb[(size_t)row * NF + n * 16 + r] = f2bf(acc[t][n][q]);
            }
        }
    }
}

// ---------------- aggregate: bf16 gather, fp32 math, bf16 out ----------------
__global__ __launch_bounds__(256) void aggregate_kernel(const ushort* __restrict__ Hb,
                                                        const float* __restrict__ dinv,
                                                        const unsigned* __restrict__ rowptr,
                                                        const uint2* __restrict__ csr,
                                                        const float* __restrict__ bias,
                                                        ushort* __restrict__ Xout, int N) {
    int gid = blockIdx.x * 256 + threadIdx.x;
    int node = gid >> 5;
    int lane = gid & 31;
    if (node >= N) return;
    float di = dinv[node];
    float sl = di * di;
    float4 b = ((const float4*)bias)[lane];
    ushort4 hv = *(const ushort4*)(Hb + (size_t)node * NF + lane * 4);
    float ax = fmaf(b2f(hv.x), sl, b.x);
    float ay = fmaf(b2f(hv.y), sl, b.y);
    float az = fmaf(b2f(hv.z), sl, b.z);
    float aw = fmaf(b2f(hv.w), sl, b.w);
    unsigned e = rowptr[node], end = rowptr[node + 1];
    for (; e + 4 <= end; e += 4) {
        uint2 m0 = csr[e + 0], m1 = csr[e + 1], m2 = csr[e + 2], m3 = csr[e + 3];
        ushort4 g0 = *(const ushort4*)(Hb + (size_t)m0.x * NF + lane * 4);
        ushort4 g1 = *(const ushort4*)(Hb + (size_t)m1.x * NF + lane * 4);
        ushort4 g2 = *(const ushort4*)(Hb + (size_t)m2.x * NF + lane * 4);
        ushort4 g3 = *(const ushort4*)(Hb + (size_t)m3.x * NF + lane * 4);
        float n0 = __uint_as_float(m0.y), n1 = __uint_as_float(m1.y);
        float n2 = __uint_as_float(m2.y), n3 = __uint_as_float(m3.y);
        ax = fmaf(b2f(g0.x), n0, ax); ay = fmaf(b2f(g0.y), n0, ay);
        az = fmaf(b2f(g0.z), n0, az); aw = fmaf(b2f(g0.w), n0, aw);
        ax = fmaf(b2f(g1.x), n1, ax); ay = fmaf(b2f(g1.y), n1, ay);
        az = fmaf(b2f(g1.z), n1, az); aw = fmaf(b2f(g1.w), n1, aw);
        ax = fmaf(b2f(g2.x), n2, ax); ay = fmaf(b2f(g2.y), n2, ay);
        az = fmaf(b2f(g2.z), n2, az); aw = fmaf(b2f(g2.w), n2, aw);
        ax = fmaf(b2f(g3.x), n3, ax); ay = fmaf(b2f(g3.y), n3, ay);
        az = fmaf(b2f(g3.z), n3, az); aw = fmaf(b2f(g3.w), n3, aw);
    }
    for (; e < end; ++e) {
        uint2 m = csr[e];
        ushort4 g = *(const ushort4*)(Hb + (size_t)m.x * NF + lane * 4);
        float nm = __uint_as_float(m.y);
        ax = fmaf(b2f(g.x), nm, ax); ay = fmaf(b2f(g.y), nm, ay);
        az = fmaf(b2f(g.z), nm, az); aw = fmaf(b2f(g.w), nm, aw);
    }
    ax = ax > 0.f ? ax : expm1f(ax);
    ay = ay > 0.f ? ay : expm1f(ay);
    az = az > 0.f ? az : expm1f(az);
    aw = aw > 0.f ? aw : expm1f(aw);
    ushort4 o;
    o.x = f2bf(ax); o.y = f2bf(ay); o.z = f2bf(az); o.w = f2bf(aw);
    *(ushort4*)(Xout + (size_t)node * NF + lane * 4) = o;
}

// ---------------- global max pool: node-parallel, atomicMax on monotone enc ----------------
// block = 256 nodes; thread = (col-group cg: 4 cols, row-group rg: 8 rows stride)
__global__ __launch_bounds__(256) void pool_kernel(const ushort* __restrict__ X,
                                                   const int* __restrict__ batch,
                                                   unsigned* __restrict__ Gx, int N) {
    __shared__ int gb[256];
    int n0 = blockIdx.x * 256;
    int tid = threadIdx.x;
    {
        int n = n0 + tid;
        gb[tid] = (n < N) ? batch[n] : -1;
    }
    __syncthreads();
    int cg = tid & 31;   // columns cg*4 .. cg*4+3
    int rg = tid >> 5;   // rows rg, rg+8, ...
    float mx = -FLT_MAX, my = -FLT_MAX, mz = -FLT_MAX, mw = -FLT_MAX;
    int curg = -1;
    for (int i = rg; i < 256; i += 8) {
        int n = n0 + i;
        if (n >= N) break;
        int g = gb[i];
        if (g != curg) {
            if (curg >= 0) {
                unsigned* p = Gx + (size_t)curg * NF + cg * 4;
                atomicMax(p + 0, fenc(mx)); atomicMax(p + 1, fenc(my));
                atomicMax(p + 2, fenc(mz)); atomicMax(p + 3, fenc(mw));
            }
            curg = g;
            mx = my = mz = mw = -FLT_MAX;
        }
        ushort4 v = *(const ushort4*)(X + (size_t)n * NF + cg * 4);
        mx = fmaxf(mx, b2f(v.x)); my = fmaxf(my, b2f(v.y));
        mz = fmaxf(mz, b2f(v.z)); mw = fmaxf(mw, b2f(v.w));
    }
    if (curg >= 0) {
        unsigned* p = Gx + (size_t)curg * NF + cg * 4;
        atomicMax(p + 0, fenc(mx)); atomicMax(p + 1, fenc(my));
        atomicMax(p + 2, fenc(mz)); atomicMax(p + 3, fenc(mw));
    }
}

// ---------------- classifier: softmax(decode(Gx) @ Wc + bc), fp32 ----------------
__global__ __launch_bounds__(128) void classify_kernel(const unsigned* __restrict__ Gx,
                                                       const float* __restrict__ Wc,
                                                       const float* __restrict__ bc,
                                                       float* __restrict__ out) {
    __shared__ float gr[NF];
    __shared__ float lg[NCLASSES];
    int g = blockIdx.x;
    int tid = threadIdx.x;
    gr[tid] = fdec(Gx[(size_t)g * NF + tid]);
    __syncthreads();
    if (tid < NCLASSES) {
        float s = bc[tid];
        for (int k = 0; k < NF; ++k) s = fmaf(gr[k], Wc[k * NCLASSES + tid], s);
        lg[tid] = s;
    }
    __syncthreads();
    if (tid == 0) {
        float m = lg[0];
        #pragma unroll
        for (int c = 1; c < NCLASSES; ++c) m = fmaxf(m, lg[c]);
        float e[NCLASSES];
        float sum = 0.f;
        #pragma unroll
        for (int c = 0; c < NCLASSES; ++c) { e[c] = expf(lg[c] - m); sum += e[c]; }
        #pragma unroll
        for (int c = 0; c < NCLASSES; ++c) out[g * NCLASSES + c] = e[c] / sum;
    }
}

extern "C" void kernel_launch(void* const* d_in, const int* in_sizes, int n_in,
                              void* d_out, int out_size, void* d_ws, size_t ws_size,
                              hipStream_t stream) {
    const float* x     = (const float*)d_in[0];
    const int*   ei    = (const int*)d_in[1];
    const int*   batch = (const int*)d_in[2];
    const float* Ws    = (const float*)d_in[3];
    const float* bs    = (const float*)d_in[4];
    const float* Wc    = (const float*)d_in[5];
    const float* bc    = (const float*)d_in[6];
    float* out = (float*)d_out;

    const int* src = ei;
    const int* dst = ei + NEDGES;

    char* ws = (char*)d_ws;
    size_t off = 0;
    auto alloc = [&](size_t bytes) -> void* {
        off = (off + 255) & ~(size_t)255;
        void* p = ws + off;
        off += bytes;
        return p;
    };
    ushort*   B0     = (ushort*)alloc(sizeof(ushort) * (size_t)NNODES * NF);
    ushort*   B1     = (ushort*)alloc(sizeof(ushort) * (size_t)NNODES * NF);
    ushort*   Hb     = (ushort*)alloc(sizeof(ushort) * (size_t)NNODES * NF);
    float*    dinvp  = (float*)alloc(sizeof(float) * NNODES);
    unsigned* cnt    = (unsigned*)alloc(sizeof(unsigned) * NNODES);
    unsigned* cursor = (unsigned*)alloc(sizeof(unsigned) * NNODES);
    unsigned* rowptr = (unsigned*)alloc(sizeof(unsigned) * (NNODES + 1));
    uint2*    csr    = (uint2*)alloc(sizeof(uint2) * NEDGES);
    unsigned* bsum   = (unsigned*)alloc(sizeof(unsigned) * SCAN_NB);
    unsigned* boff   = (unsigned*)alloc(sizeof(unsigned) * SCAN_NB);
    short*    Wf     = (short*)alloc(sizeof(short) * 3 * 16384);
    unsigned* Gx     = (unsigned*)alloc(sizeof(unsigned) * NGRAPHS * NF);

    hipMemsetAsync(cnt, 0, sizeof(unsigned) * NNODES, stream);
    hipMemsetAsync(Gx, 0, sizeof(unsigned) * NGRAPHS * NF, stream);
    wprep_kernel<<<3, 256, 0, stream>>>(Ws, Wf);
    hist_kernel<<<(NEDGES + 255) / 256, 256, 0, stream>>>(dst, cnt, NEDGES);
    dinv_kernel<<<(NNODES + 255) / 256, 256, 0, stream>>>(cnt, dinvp, NNODES);
    scanA_kernel<<<SCAN_NB, 256, 0, stream>>>(cnt, bsum, NNODES);
    scanB_kernel<<<1, 64, 0, stream>>>(bsum, boff, rowptr + NNODES);
    scanC_kernel<<<SCAN_NB, 256, 0, stream>>>(cnt, boff, rowptr, cursor, NNODES);
    fill_kernel<<<(NEDGES + 255) / 256, 256, 0, stream>>>(src, dst, dinvp, cursor, csr, NEDGES);

    int gemm_grid = (NNODES + 127) / 128;   // 782
    int agg_grid  = (NNODES * 32) / 256;    // 12500 exact

    gemm_mfma_kernel<true><<<gemm_grid, 256, 0, stream>>>(x, Wf + 0 * 16384, Hb, NNODES);
    aggregate_kernel<<<agg_grid, 256, 0, stream>>>(Hb, dinvp, rowptr, csr, bs + 0 * NF, B1, NNODES);
    gemm_mfma_kernel<false><<<gemm_grid, 256, 0, stream>>>(B1, Wf + 1 * 16384, Hb, NNODES);
    aggregate_kernel<<<agg_grid, 256, 0, stream>>>(Hb, dinvp, rowptr, csr, bs + 1 * NF, B0, NNODES);
    gemm_mfma_kernel<false><<<gemm_grid, 256, 0, stream>>>(B0, Wf + 2 * 16384, Hb, NNODES);
    aggregate_kernel<<<agg_grid, 256, 0, stream>>>(Hb, dinvp, rowptr, csr, bs + 2 * NF, B1, NNODES);

    pool_kernel<<<(NNODES + 255) / 256, 256, 0, stream>>>(B1, batch, Gx, NNODES);
    classify_kernel<<<NGRAPHS, 128, 0, stream>>>(Gx, Wc, bc, out);
}